// Round 4
// baseline (257.731 us; speedup 1.0000x reference)
//
#include <hip/hip_runtime.h>

#define KDIM 32
#define EPSC 1e-6f
#define NSLOTS 2048

// ============ Kernel A: per-block partial M/s with inline softmax ============
// For a 32-sample chunk: recompute softmax(Z[:,node]) per sampled column from
// raw Z, form ZG, write partial M (32x32) and partial s (32) for this block.
__global__ __launch_bounds__(1024) void reduce_M_partial(
    const float* __restrict__ Z_i, const float* __restrict__ Z_j,
    const float* __restrict__ Gate,
    const int* __restrict__ si, const int* __restrict__ sj,
    float* __restrict__ Mpart, float* __restrict__ Spart,
    int n_i, int n_j, int m_i, int m)
{
    __shared__ float Zl[32][33], Gl[32][33];
    __shared__ float cmax[32], cinv[32];
    __shared__ int nodeL[32];
    int q = threadIdx.x, p = threadIdx.y;
    int m0 = blockIdx.x * 32;
    if (p == 0) {
        int mi = m0 + q;
        nodeL[q] = (mi < m) ? ((mi < m_i) ? si[mi] : sj[mi - m_i]) : -1;
    }
    __syncthreads();
    int nq = nodeL[q];
    float zv = 0.f;
    if (nq >= 0) {
        int mi = m0 + q;
        const float* Zr = (mi < m_i) ? Z_i : Z_j;
        int n = (mi < m_i) ? n_i : n_j;
        zv = Zr[p * n + nq];
    }
    Zl[p][q] = zv;
    __syncthreads();
    if (p == 0) {   // serial per-column softmax stats (32 lanes, tiny)
        float mx = -1e30f;
        #pragma unroll
        for (int r = 0; r < 32; r++) mx = fmaxf(mx, Zl[r][q]);
        float s = 0.f;
        #pragma unroll
        for (int r = 0; r < 32; r++) s += __expf(Zl[r][q] - mx);
        cmax[q] = mx; cinv[q] = 1.f / s;
    }
    __syncthreads();
    // own-cell RMW: safe (all cross-reads of raw Zl completed above)
    float zs = (nq >= 0) ? __expf(Zl[p][q] - cmax[q]) * cinv[q] : 0.f;
    Zl[p][q] = zs;
    __syncthreads();
    // Gl[p][q] = zsoft_sample_p[q] * sigmoid(Gate[node_p][q])  (raw node id, faithful)
    int np_ = nodeL[p];
    float gv = 0.f;
    if (np_ >= 0) {
        float g = 1.f / (1.f + __expf(-Gate[(size_t)np_ * KDIM + q]));
        gv = Zl[q][p] * g;
    }
    Gl[p][q] = gv;
    __syncthreads();
    float acc = 0.f;
    #pragma unroll
    for (int s = 0; s < 32; s++) acc = fmaf(Zl[p][s], Gl[s][q], acc);
    Mpart[(size_t)blockIdx.x * 1024 + p * 32 + q] = acc;
    if (p == 0) {
        float ss = 0.f;
        #pragma unroll
        for (int s = 0; s < 32; s++) ss += Gl[s][q];
        Spart[(size_t)blockIdx.x * 32 + q] = ss;
    }
}

// ============ Kernel B: reduce partials -> AZC (in LDS) -> X_all ============
// Each block redundantly reduces partials and computes AZC, then computes
// latent positions for its 256 nodes (inline register softmax from raw Z).
// Block 0 additionally zeros slots+counter for kernel C.
__global__ __launch_bounds__(256) void xall_azc(
    const float* __restrict__ Mpart, const float* __restrict__ Spart, int nblkA,
    const float* __restrict__ Amat,
    const float* __restrict__ Z_i, const float* __restrict__ Z_j,
    float* __restrict__ Xi_all, float* __restrict__ Xj_all,
    float* __restrict__ slots, int* __restrict__ counter,
    int n_i, int n_j)
{
    __shared__ float Cn[32][33];
    __shared__ float Al[32][32];
    __shared__ float Ss[32];
    int t = threadIdx.x;
    if (blockIdx.x == 0) {
        for (int i = t; i < NSLOTS; i += 256) slots[i] = 0.f;
        if (t == 0) *counter = 0;
    }
    for (int idx = t; idx < 1024; idx += 256) {
        float s = 0.f;
        for (int b = 0; b < nblkA; b++) s += Mpart[(size_t)b * 1024 + idx];
        Cn[idx >> 5][idx & 31] = s;
    }
    if (t < 32) {
        float s = 0.f;
        for (int b = 0; b < nblkA; b++) s += Spart[(size_t)b * 32 + t];
        Ss[t] = 1.f / s;
    }
    __syncthreads();
    for (int idx = t; idx < 1024; idx += 256) Cn[idx >> 5][idx & 31] *= Ss[idx & 31];
    __syncthreads();
    for (int idx = t; idx < 1024; idx += 256) {
        int d = idx >> 5, q = idx & 31;
        float s = 0.f;
        #pragma unroll
        for (int j = 0; j < 32; j++) s = fmaf(Amat[d * 32 + j], Cn[j][q], s);
        Al[d][q] = s;
    }
    __syncthreads();
    int node = blockIdx.x * 256 + t;
    const float* Zr; float* X; int n, c;
    if (node < n_i)            { Zr = Z_i; X = Xi_all; n = n_i; c = node; }
    else if (node < n_i + n_j) { Zr = Z_j; X = Xj_all; n = n_j; c = node - n_i; }
    else return;
    float z[32];
    float mx = -1e30f;
    #pragma unroll
    for (int p = 0; p < 32; p++) { z[p] = Zr[p * n + c]; mx = fmaxf(mx, z[p]); }
    float ssum = 0.f;
    #pragma unroll
    for (int p = 0; p < 32; p++) { z[p] = __expf(z[p] - mx); ssum += z[p]; }
    float inv = 1.f / ssum;
    #pragma unroll
    for (int p = 0; p < 32; p++) z[p] *= inv;
    #pragma unroll
    for (int dd = 0; dd < 32; dd++) {
        float x = 0.f;
        #pragma unroll
        for (int p = 0; p < 32; p++) x = fmaf(Al[dd][p], z[p], x);
        X[(size_t)c * 32 + dd] = x;
    }
}

// ============ Kernel C: pairwise tiles + edge blocks + last-block final ============
__global__ __launch_bounds__(256) void pairwise_edge_final(
    const float* __restrict__ Xi_all, const float* __restrict__ Xj_all,
    const int* __restrict__ si, const int* __restrict__ sj,
    const int* __restrict__ sei, const int* __restrict__ sej,
    const float* __restrict__ beta, const float* __restrict__ gamma,
    int m_i, int m_j, int E, int nbi, int nbj, int nblkTot,
    float* __restrict__ slots, int* __restrict__ counter, float* __restrict__ out)
{
    __shared__ float XiL[64][33], XjL[64][33];
    __shared__ float bl[64], gl[64];
    __shared__ float wsum[4];
    __shared__ int lastFlag;
    int bid = blockIdx.x;
    int npair = nbi * nbj;
    int tid = threadIdx.x;
    float part = 0.f;

    if (bid < npair) {
        int i0 = (bid / nbj) * 64, j0 = (bid % nbj) * 64;
        #pragma unroll
        for (int l = 0; l < 8; l++) {
            int idx = tid + l * 256;
            int row = idx >> 5, dd = idx & 31;
            int gi = i0 + row;
            XiL[row][dd] = (gi < m_i) ? Xi_all[(size_t)si[gi] * 32 + dd] : 0.f;
            int gj = j0 + row;
            XjL[row][dd] = (gj < m_j) ? Xj_all[(size_t)sj[gj] * 32 + dd] : 0.f;
        }
        if (tid < 64) {
            bl[tid] = (i0 + tid < m_i) ? beta[si[i0 + tid]] : 0.f;
            gl[tid] = (j0 + tid < m_j) ? gamma[sj[j0 + tid]] : 0.f;
        }
        __syncthreads();
        int ti = tid >> 4, tj = tid & 15;
        float f[4][4] = {};
        #pragma unroll 4
        for (int dd = 0; dd < 32; dd++) {
            float a0 = XiL[ti * 4 + 0][dd] + EPSC;
            float a1 = XiL[ti * 4 + 1][dd] + EPSC;
            float a2 = XiL[ti * 4 + 2][dd] + EPSC;
            float a3 = XiL[ti * 4 + 3][dd] + EPSC;
            float b0 = XjL[tj * 4 + 0][dd];
            float b1 = XjL[tj * 4 + 1][dd];
            float b2 = XjL[tj * 4 + 2][dd];
            float b3 = XjL[tj * 4 + 3][dd];
            float t0;
            t0 = a0 - b0; f[0][0] = fmaf(t0, t0, f[0][0]);
            t0 = a0 - b1; f[0][1] = fmaf(t0, t0, f[0][1]);
            t0 = a0 - b2; f[0][2] = fmaf(t0, t0, f[0][2]);
            t0 = a0 - b3; f[0][3] = fmaf(t0, t0, f[0][3]);
            t0 = a1 - b0; f[1][0] = fmaf(t0, t0, f[1][0]);
            t0 = a1 - b1; f[1][1] = fmaf(t0, t0, f[1][1]);
            t0 = a1 - b2; f[1][2] = fmaf(t0, t0, f[1][2]);
            t0 = a1 - b3; f[1][3] = fmaf(t0, t0, f[1][3]);
            t0 = a2 - b0; f[2][0] = fmaf(t0, t0, f[2][0]);
            t0 = a2 - b1; f[2][1] = fmaf(t0, t0, f[2][1]);
            t0 = a2 - b2; f[2][2] = fmaf(t0, t0, f[2][2]);
            t0 = a2 - b3; f[2][3] = fmaf(t0, t0, f[2][3]);
            t0 = a3 - b0; f[3][0] = fmaf(t0, t0, f[3][0]);
            t0 = a3 - b1; f[3][1] = fmaf(t0, t0, f[3][1]);
            t0 = a3 - b2; f[3][2] = fmaf(t0, t0, f[3][2]);
            t0 = a3 - b3; f[3][3] = fmaf(t0, t0, f[3][3]);
        }
        int ib = i0 + ti * 4, jb = j0 + tj * 4;
        #pragma unroll
        for (int r = 0; r < 4; r++) {
            #pragma unroll
            for (int c = 0; c < 4; c++) {
                if (ib + r < m_i && jb + c < m_j) {
                    float dist = sqrtf(f[r][c]);
                    part += __expf(bl[ti * 4 + r] + gl[tj * 4 + c] - dist);
                }
            }
        }
        part = -part;   // pairwise term is subtracted
    } else {
        int e = (bid - npair) * 256 + tid;
        if (e < E) {
            int a = sei[e], b = sej[e];
            const float4* xa = (const float4*)(Xi_all + (size_t)a * 32);
            const float4* xb = (const float4*)(Xj_all + (size_t)b * 32);
            float s = 0.f;
            #pragma unroll
            for (int qq = 0; qq < 8; qq++) {
                float4 va = xa[qq], vb = xb[qq];
                float t0;
                t0 = va.x - vb.x + EPSC; s = fmaf(t0, t0, s);
                t0 = va.y - vb.y + EPSC; s = fmaf(t0, t0, s);
                t0 = va.z - vb.z + EPSC; s = fmaf(t0, t0, s);
                t0 = va.w - vb.w + EPSC; s = fmaf(t0, t0, s);
            }
            part = beta[a] + gamma[b] - sqrtf(s);
        }
        __syncthreads();   // match pairwise path barrier count
    }

    // block reduction -> one atomic per block
    float v = part;
    #pragma unroll
    for (int o = 32; o > 0; o >>= 1) v += __shfl_down(v, o, 64);
    if ((tid & 63) == 0) wsum[tid >> 6] = v;
    __syncthreads();
    if (tid == 0) {
        float tot = wsum[0] + wsum[1] + wsum[2] + wsum[3];
        atomicAdd(&slots[bid & (NSLOTS - 1)], tot);
        __threadfence();
        int ticket = atomicAdd(counter, 1);
        lastFlag = (ticket == nblkTot - 1) ? 1 : 0;
    }
    __syncthreads();
    if (lastFlag) {
        __threadfence();
        float fv = 0.f;
        for (int i = tid; i < NSLOTS; i += 256)
            fv += __hip_atomic_load(&slots[i], __ATOMIC_RELAXED, __HIP_MEMORY_SCOPE_AGENT);
        #pragma unroll
        for (int o = 32; o > 0; o >>= 1) fv += __shfl_down(fv, o, 64);
        if ((tid & 63) == 0) wsum[tid >> 6] = fv;
        __syncthreads();
        if (tid == 0) out[0] = wsum[0] + wsum[1] + wsum[2] + wsum[3];
    }
}

extern "C" void kernel_launch(void* const* d_in, const int* in_sizes, int n_in,
                              void* d_out, int out_size, void* d_ws, size_t ws_size,
                              hipStream_t stream) {
    const float* beta  = (const float*)d_in[0];
    const float* gamma = (const float*)d_in[1];
    const float* Amat  = (const float*)d_in[2];
    const float* Z_i   = (const float*)d_in[3];
    const float* Z_j   = (const float*)d_in[4];
    const float* Gate  = (const float*)d_in[5];
    const int*   si    = (const int*)d_in[6];
    const int*   sj    = (const int*)d_in[7];
    const int*   sei   = (const int*)d_in[8];
    const int*   sej   = (const int*)d_in[9];

    int n_i = in_sizes[0], n_j = in_sizes[1];
    int m_i = in_sizes[6], m_j = in_sizes[7], E = in_sizes[8];
    int m = m_i + m_j;
    int nTot = n_i + n_j;
    int nblkA = (m + 31) / 32;

    float* ws = (float*)d_ws;
    float* Mpart  = ws; ws += (size_t)nblkA * 1024;
    float* Spart  = ws; ws += (size_t)nblkA * 32;
    float* slots  = ws; ws += NSLOTS;
    int*   counter = (int*)ws; ws += 4;          // padded to 16B
    float* Xi_all = ws; ws += (size_t)n_i * KDIM;
    float* Xj_all = ws; ws += (size_t)n_j * KDIM;

    reduce_M_partial<<<nblkA, dim3(32, 32), 0, stream>>>(
        Z_i, Z_j, Gate, si, sj, Mpart, Spart, n_i, n_j, m_i, m);

    xall_azc<<<(nTot + 255) / 256, 256, 0, stream>>>(
        Mpart, Spart, nblkA, Amat, Z_i, Z_j, Xi_all, Xj_all,
        slots, counter, n_i, n_j);

    int nbi = (m_i + 63) / 64, nbj = (m_j + 63) / 64;
    int nedge = (E + 255) / 256;
    int nblkTot = nbi * nbj + nedge;
    pairwise_edge_final<<<nblkTot, 256, 0, stream>>>(
        Xi_all, Xj_all, si, sj, sei, sej, beta, gamma,
        m_i, m_j, E, nbi, nbj, nblkTot, slots, counter, (float*)d_out);
}